// Round 9
// baseline (23359.822 us; speedup 1.0000x reference)
//
#include <hip/hip_runtime.h>

#define NRES 2048
#define NBLK 256
#define RBUF 4  // rotation depth; producers lead slowest consumer by <=2 slots

typedef unsigned long long u64;
typedef unsigned int u32;

// ---------------- W transpose: Wt[j][i] = W[i][j] ----------------
__global__ __launch_bounds__(256) void transpose_k(const float* __restrict__ W,
                                                   float* __restrict__ Wt) {
  __shared__ float tile[32][33];
  const int tx = threadIdx.x, ty = threadIdx.y;
  const int x = blockIdx.x * 32 + tx;
  const int y0 = blockIdx.y * 32;
#pragma unroll
  for (int j = ty; j < 32; j += 8)
    tile[j][tx] = W[(size_t)(y0 + j) * NRES + x];
  __syncthreads();
  const int x2 = blockIdx.y * 32 + tx;
  const int y2 = blockIdx.x * 32;
#pragma unroll
  for (int j = ty; j < 32; j += 8)
    Wt[(size_t)(y2 + j) * NRES + x2] = tile[tx][j];
}

// ---------------- uproj GEMM: U[M,N] = X[M,K] @ B[K,N], fp32 ----------------
__global__ __launch_bounds__(256) void gemm_uproj(const float* __restrict__ X,
                                                  const float* __restrict__ B,
                                                  float* __restrict__ U,
                                                  int M, int N, int K) {
  __shared__ float As[16][128];  // As[k][m]
  __shared__ float Bs[16][128];  // Bs[k][n]
  const int tid = threadIdx.x;
  const int tx = tid & 15, ty = tid >> 4;
  const int m0 = blockIdx.y * 128, n0 = blockIdx.x * 128;

  float acc[8][8];
#pragma unroll
  for (int i = 0; i < 8; i++)
#pragma unroll
    for (int j = 0; j < 8; j++) acc[i][j] = 0.f;

  const int sam = tid >> 1, sak = (tid & 1) * 8;   // A staging: row, k-half
  const int sbk = tid >> 4, sbn = (tid & 15) * 8;  // B staging: k, n-start

  for (int k0 = 0; k0 < K; k0 += 16) {
    const float* ap = X + (size_t)(m0 + sam) * K + k0 + sak;
    float4 a0 = *(const float4*)(ap);
    float4 a1 = *(const float4*)(ap + 4);
    As[sak + 0][sam] = a0.x; As[sak + 1][sam] = a0.y;
    As[sak + 2][sam] = a0.z; As[sak + 3][sam] = a0.w;
    As[sak + 4][sam] = a1.x; As[sak + 5][sam] = a1.y;
    As[sak + 6][sam] = a1.z; As[sak + 7][sam] = a1.w;
    const float* bp = B + (size_t)(k0 + sbk) * N + n0 + sbn;
    *(float4*)&Bs[sbk][sbn]     = *(const float4*)(bp);
    *(float4*)&Bs[sbk][sbn + 4] = *(const float4*)(bp + 4);
    __syncthreads();
#pragma unroll
    for (int kk = 0; kk < 16; kk++) {
      float a[8], b[8];
      *(float4*)&a[0] = *(const float4*)&As[kk][ty * 8];
      *(float4*)&a[4] = *(const float4*)&As[kk][ty * 8 + 4];
      *(float4*)&b[0] = *(const float4*)&Bs[kk][tx * 8];
      *(float4*)&b[4] = *(const float4*)&Bs[kk][tx * 8 + 4];
#pragma unroll
      for (int i = 0; i < 8; i++)
#pragma unroll
        for (int j = 0; j < 8; j++) acc[i][j] += a[i] * b[j];
    }
    __syncthreads();
  }
#pragma unroll
  for (int i = 0; i < 8; i++) {
    float* dst = U + (size_t)(m0 + ty * 8 + i) * N + n0 + tx * 8;
    *(float4*)dst       = *(float4*)&acc[i][0];
    *(float4*)(dst + 4) = *(float4*)&acc[i][4];
  }
}

// ---------------- persistent ESN scan: register-resident, barrier-free -----
// 256 blocks x 256 threads, cooperative. Wave wv of block b owns columns
// j0 = 8b + 2wv and j0+1. Lane l holds W rows {l + 64k}, k=0..31 for BOTH
// columns (wA/wB, 64 VGPRs) and polls exactly those 32 tagged words of
// v_{t-1}, latching arrivals into a register array vprev[32] (fixed-order
// dot afterwards -> deterministic accumulation). NO LDS, NO barriers in the
// whole loop: each wave is an independent sync participant. Tail after the
// last word arrives: 64 reg-FMAs + two 6-step butterfly reduces + exp +
// two atomic swaps (lanes 0 and 1 publish concurrently) ~= 0.12us, vs the
// ~0.45us LDS-fill + barrier + LDS-dot tail of the previous structure.
//
// Sync invariant (RBUF=4): for a wave to publish step s it observed all of
// step s-1 -> every wave published s-1 -> slowest wave is IN step s-1 or
// later. So producers lead the slowest consumer's read slot (t-1) by at
// most 2 slots < 4: no in-flight slot is ever overwritten. Tags are zeroed
// each launch; tag values are exact-match on t so stale rotation data is
// inert.
__global__ __launch_bounds__(256, 1) void esn_scan(const float* __restrict__ Wt,
                                                   const float* __restrict__ W,
                                                   u64* vtag,
                                                   float* __restrict__ UY,
                                                   int T) {
  const int b = blockIdx.x;
  const int tid = threadIdx.x;
  const int wv = tid >> 6;
  const int lane = tid & 63;
  const int j0 = b * 8 + 2 * wv;

  // one-time: W fragments for both owned columns (coalesced via Wt)
  float wA[32], wB[32];
  if (Wt) {
    const float* r0 = Wt + (size_t)j0 * NRES;
    const float* r1 = Wt + (size_t)(j0 + 1) * NRES;
#pragma unroll
    for (int k = 0; k < 32; ++k) {
      wA[k] = r0[lane + 64 * k];
      wB[k] = r1[lane + 64 * k];
    }
  } else {
#pragma unroll
    for (int k = 0; k < 32; ++k) {
      wA[k] = W[(size_t)(lane + 64 * k) * NRES + j0];
      wB[k] = W[(size_t)(lane + 64 * k) * NRES + j0 + 1];
    }
  }

  float vprev[32];  // v_{t-1}[lane + 64k], register-resident
#pragma unroll
  for (int k = 0; k < 32; ++k) vprev[k] = 0.f;
  float vold = 0.f;  // own column's v_{t-1}; meaningful on lanes 0,1

  for (int t = 0; t < T; ++t) {
    // u_t for the two owned columns, in flight during the poll
    float u = 0.f;
    if (lane < 2) u = UY[(size_t)t * NRES + j0 + lane];

    if (t > 0) {
      u64* src = vtag + (size_t)((t - 1) & (RBUF - 1)) * NRES;
      u32 done = 0;
      while (done != 0xFFFFFFFFu) {
        u64 w[32];
#pragma unroll
        for (int k = 0; k < 32; ++k)
          if (!(done & (1u << k)))
            w[k] = __hip_atomic_load(&src[lane + 64 * k], __ATOMIC_RELAXED,
                                     __HIP_MEMORY_SCOPE_AGENT);
#pragma unroll
        for (int k = 0; k < 32; ++k) {
          if (!(done & (1u << k)) && (u32)(w[k] >> 32) == (u32)t) {
            vprev[k] = __uint_as_float((u32)w[k]);
            done |= 1u << k;
          }
        }
      }
    }

    // fixed-order register dot (deterministic), 2 chains per column
    float a0 = 0.f, a1 = 0.f, c0 = 0.f, c1 = 0.f;
#pragma unroll
    for (int k = 0; k < 32; k += 2) {
      a0 += wA[k] * vprev[k];
      a1 += wA[k + 1] * vprev[k + 1];
      c0 += wB[k] * vprev[k];
      c1 += wB[k + 1] * vprev[k + 1];
    }
    float accA = a0 + a1, accB = c0 + c1;
    // full-wave butterfly: sum lands in every lane
#pragma unroll
    for (int off = 32; off >= 1; off >>= 1) {
      accA += __shfl_xor(accA, off);
      accB += __shfl_xor(accB, off);
    }

    if (lane < 2) {
      float acc = (lane == 0) ? accA : accB;
      float xx = acc + u;
      float e = __expf(2.f * xx);        // v_exp_f32 path
      float th = 1.f - 2.f / (e + 1.f);  // == tanh(xx) exactly
      float vnew = 0.5f * vold + 0.5f * th;
      vold = vnew;
      const int j = j0 + lane;
      UY[(size_t)t * NRES + j] = vnew;  // states[t][j]
      u64 w = ((u64)(u32)(t + 1) << 32) | (u64)__float_as_uint(vnew);
      (void)__hip_atomic_exchange(&vtag[(size_t)(t & (RBUF - 1)) * NRES + j],
                                  w, __ATOMIC_RELAXED,
                                  __HIP_MEMORY_SCOPE_AGENT);
    }
  }
}

extern "C" void kernel_launch(void* const* d_in, const int* in_sizes, int n_in,
                              void* d_out, int out_size, void* d_ws, size_t ws_size,
                              hipStream_t stream) {
  const float* x   = (const float*)d_in[0];
  const float* Win = (const float*)d_in[1];
  const float* W   = (const float*)d_in[2];
  float* U = (float*)d_out;

  const int T = out_size / NRES;  // 4096
  const int K = in_sizes[0] / T;  // 4096 (nInput)

  char* ws = (char*)d_ws;
  u64* vtag = (u64*)ws;  // [RBUF][NRES] = 64 KB @ 0
  const size_t vtag_bytes = (size_t)RBUF * NRES * sizeof(u64);
  float* Wt = nullptr;
  if (ws_size >= (1u << 20) + (size_t)NRES * NRES * sizeof(float))
    Wt = (float*)(ws + (1u << 20));  // 16 MB @ 1 MB

  // tags must be zeroed every launch (replays would otherwise see stale epochs)
  hipMemsetAsync(vtag, 0, vtag_bytes, stream);

  if (Wt) transpose_k<<<dim3(NRES / 32, NRES / 32), dim3(32, 8), 0, stream>>>(W, Wt);

  gemm_uproj<<<dim3(NRES / 128, T / 128), 256, 0, stream>>>(x, Win, U, T, NRES, K);

  void* args[] = {(void*)&Wt, (void*)&W, (void*)&vtag, (void*)&U, (void*)&T};
  hipLaunchCooperativeKernel((const void*)esn_scan, dim3(NBLK), dim3(256), args,
                             0, stream);
}

// Round 10
// 14546.053 us; speedup vs baseline: 1.6059x; 1.6059x over previous
//
#include <hip/hip_runtime.h>

#define NRES 2048
#define NBLK 256
#define RBUF 4  // rotation depth; max inter-block skew is 1 step -> >=3 race-free

typedef unsigned long long u64;
typedef unsigned int u32;

// ---------------- W transpose: Wt[j][i] = W[i][j] ----------------
__global__ __launch_bounds__(256) void transpose_k(const float* __restrict__ W,
                                                   float* __restrict__ Wt) {
  __shared__ float tile[32][33];
  const int tx = threadIdx.x, ty = threadIdx.y;
  const int x = blockIdx.x * 32 + tx;
  const int y0 = blockIdx.y * 32;
#pragma unroll
  for (int j = ty; j < 32; j += 8)
    tile[j][tx] = W[(size_t)(y0 + j) * NRES + x];
  __syncthreads();
  const int x2 = blockIdx.y * 32 + tx;
  const int y2 = blockIdx.x * 32;
#pragma unroll
  for (int j = ty; j < 32; j += 8)
    Wt[(size_t)(y2 + j) * NRES + x2] = tile[tx][j];
}

// ---------------- uproj GEMM: U[M,N] = X[M,K] @ B[K,N], fp32 ----------------
__global__ __launch_bounds__(256) void gemm_uproj(const float* __restrict__ X,
                                                  const float* __restrict__ B,
                                                  float* __restrict__ U,
                                                  int M, int N, int K) {
  __shared__ float As[16][128];  // As[k][m]
  __shared__ float Bs[16][128];  // Bs[k][n]
  const int tid = threadIdx.x;
  const int tx = tid & 15, ty = tid >> 4;
  const int m0 = blockIdx.y * 128, n0 = blockIdx.x * 128;

  float acc[8][8];
#pragma unroll
  for (int i = 0; i < 8; i++)
#pragma unroll
    for (int j = 0; j < 8; j++) acc[i][j] = 0.f;

  const int sam = tid >> 1, sak = (tid & 1) * 8;   // A staging: row, k-half
  const int sbk = tid >> 4, sbn = (tid & 15) * 8;  // B staging: k, n-start

  for (int k0 = 0; k0 < K; k0 += 16) {
    const float* ap = X + (size_t)(m0 + sam) * K + k0 + sak;
    float4 a0 = *(const float4*)(ap);
    float4 a1 = *(const float4*)(ap + 4);
    As[sak + 0][sam] = a0.x; As[sak + 1][sam] = a0.y;
    As[sak + 2][sam] = a0.z; As[sak + 3][sam] = a0.w;
    As[sak + 4][sam] = a1.x; As[sak + 5][sam] = a1.y;
    As[sak + 6][sam] = a1.z; As[sak + 7][sam] = a1.w;
    const float* bp = B + (size_t)(k0 + sbk) * N + n0 + sbn;
    *(float4*)&Bs[sbk][sbn]     = *(const float4*)(bp);
    *(float4*)&Bs[sbk][sbn + 4] = *(const float4*)(bp + 4);
    __syncthreads();
#pragma unroll
    for (int kk = 0; kk < 16; kk++) {
      float a[8], b[8];
      *(float4*)&a[0] = *(const float4*)&As[kk][ty * 8];
      *(float4*)&a[4] = *(const float4*)&As[kk][ty * 8 + 4];
      *(float4*)&b[0] = *(const float4*)&Bs[kk][tx * 8];
      *(float4*)&b[4] = *(const float4*)&Bs[kk][tx * 8 + 4];
#pragma unroll
      for (int i = 0; i < 8; i++)
#pragma unroll
        for (int j = 0; j < 8; j++) acc[i][j] += a[i] * b[j];
    }
    __syncthreads();
  }
#pragma unroll
  for (int i = 0; i < 8; i++) {
    float* dst = U + (size_t)(m0 + ty * 8 + i) * N + n0 + tx * 8;
    *(float4*)dst       = *(float4*)&acc[i][0];
    *(float4*)(dst + 4) = *(float4*)&acc[i][4];
  }
}

// ---------------- persistent ESN scan, tagged-value sync, PACED poll --------
// 256 blocks x 256 threads, cooperative (1 block/CU). Block b owns columns
// j in [8b, 8b+8): wave wv half h -> j = 8b + 2wv + h; sub-lane s (0..31)
// holds W[:,j] elements {2s+64k, 2s+64k+1}, k=0..31 (64 floats in VGPRs).
//
// Sync: v_t[j] published as one 64-bit word {tag=t+1, f32 bits} via
// fire-and-forget agent atomic swap (commits at the coherence point).
// R9 post-mortem arithmetic: the R4 unguarded poll demanded ~45 TB/s from
// the MALL/Infinity-Cache (256 blocks x 16KB rounds x ~11 rounds/us) --
// saturating it, so the critical publish/observe requests sat in deep
// queues. Fix: (1) GUARDED issue -- only pending words are re-loaded
// (exec-masked; loads still cluster); (2) s_sleep(2) (~53ns) after each
// unsuccessful round. Together: ~5x less poll traffic, fabric out of
// saturation, at +<30ns expected delay on the last arrival.
// v_lds double-buffered: ONE barrier per step. v_old[j] in a register on
// the publishing lane. tanh via exact identity 1 - 2/(e^2x + 1).
__global__ __launch_bounds__(256, 1) void esn_scan(const float* __restrict__ Wt,
                                                   const float* __restrict__ W,
                                                   u64* vtag,
                                                   float* __restrict__ UY,
                                                   int T) {
  __shared__ float v_lds[2][NRES];
  const int b = blockIdx.x;
  const int tid = threadIdx.x;
  const int wv = tid >> 6;
  const int lane = tid & 63;
  const int h = lane >> 5;
  const int s = lane & 31;
  const int j = b * 8 + wv * 2 + h;

  // one-time: load column j of W into registers (coalesced via Wt)
  float2 w2[32];
  if (Wt) {
    const float2* wrow = (const float2*)(Wt + (size_t)j * NRES);
#pragma unroll
    for (int k = 0; k < 32; ++k) w2[k] = wrow[s + 32 * k];
  } else {
#pragma unroll
    for (int k = 0; k < 32; ++k) {
      w2[k].x = W[(size_t)(2 * s + 64 * k) * NRES + j];
      w2[k].y = W[(size_t)(2 * s + 64 * k + 1) * NRES + j];
    }
  }

  float vold = 0.f;  // v_{t-1}[j], live on s==0 lanes only
#pragma unroll
  for (int q = 0; q < 8; ++q) v_lds[0][tid + 256 * q] = 0.f;
  __syncthreads();

  for (int t = 0; t < T; ++t) {
    const int buf = t & 1;
    const size_t idx = (size_t)t * NRES + j;
    float u = (s == 0) ? UY[idx] : 0.f;  // in flight during the poll

    if (t > 0) {
      u64* src = vtag + (size_t)((t - 1) & (RBUF - 1)) * NRES;
      unsigned done = 0;
      while (true) {
        u64 w[8];
        // guarded issue: only pending words hit the fabric; independent
        // loads still cluster into parallel issue (R3 evidence)
#pragma unroll
        for (int q = 0; q < 8; ++q)
          if (!(done & (1u << q)))
            w[q] = __hip_atomic_load(&src[tid + 256 * q], __ATOMIC_RELAXED,
                                     __HIP_MEMORY_SCOPE_AGENT);
#pragma unroll
        for (int q = 0; q < 8; ++q) {
          if (!(done & (1u << q)) && (u32)(w[q] >> 32) == (u32)t) {
            v_lds[buf][tid + 256 * q] = __uint_as_float((u32)w[q]);
            done |= 1u << q;
          }
        }
        if (done == 0xFFu) break;
        __builtin_amdgcn_s_sleep(2);  // ~128 cyc: pace rounds, de-saturate
      }
      __syncthreads();
    }

    // dot(v, W[:,j]) : 32 x float2, 2-way LDS aliasing (free), 2 acc chains
    float acc0 = 0.f, acc1 = 0.f;
#pragma unroll
    for (int k = 0; k < 32; k += 2) {
      float2 va = *(const float2*)&v_lds[buf][2 * s + 64 * k];
      float2 vb = *(const float2*)&v_lds[buf][2 * s + 64 * (k + 1)];
      acc0 += w2[k].x * va.x + w2[k].y * va.y;
      acc1 += w2[k + 1].x * vb.x + w2[k + 1].y * vb.y;
    }
    float acc = acc0 + acc1;
    // butterfly reduce across the 32 sub-lanes of each half-wave
#pragma unroll
    for (int off = 16; off >= 1; off >>= 1) acc += __shfl_xor(acc, off);

    if (s == 0) {
      float xx = acc + u;
      float e = __expf(2.f * xx);        // v_exp_f32 path
      float th = 1.f - 2.f / (e + 1.f);  // == tanh(xx) exactly
      float vnew = 0.5f * vold + 0.5f * th;
      vold = vnew;
      UY[idx] = vnew;  // states[t][j]
      u64 w = ((u64)(u32)(t + 1) << 32) | (u64)__float_as_uint(vnew);
      (void)__hip_atomic_exchange(&vtag[(size_t)(t & (RBUF - 1)) * NRES + j],
                                  w, __ATOMIC_RELAXED,
                                  __HIP_MEMORY_SCOPE_AGENT);
    }
  }
}

extern "C" void kernel_launch(void* const* d_in, const int* in_sizes, int n_in,
                              void* d_out, int out_size, void* d_ws, size_t ws_size,
                              hipStream_t stream) {
  const float* x   = (const float*)d_in[0];
  const float* Win = (const float*)d_in[1];
  const float* W   = (const float*)d_in[2];
  float* U = (float*)d_out;

  const int T = out_size / NRES;  // 4096
  const int K = in_sizes[0] / T;  // 4096 (nInput)

  char* ws = (char*)d_ws;
  u64* vtag = (u64*)ws;  // [RBUF][NRES] = 64 KB @ 0
  const size_t vtag_bytes = (size_t)RBUF * NRES * sizeof(u64);
  float* Wt = nullptr;
  if (ws_size >= (1u << 20) + (size_t)NRES * NRES * sizeof(float))
    Wt = (float*)(ws + (1u << 20));  // 16 MB @ 1 MB

  // tags must be zeroed every launch (replays would otherwise see stale epochs)
  hipMemsetAsync(vtag, 0, vtag_bytes, stream);

  if (Wt) transpose_k<<<dim3(NRES / 32, NRES / 32), dim3(32, 8), 0, stream>>>(W, Wt);

  gemm_uproj<<<dim3(NRES / 128, T / 128), 256, 0, stream>>>(x, Win, U, T, NRES, K);

  void* args[] = {(void*)&Wt, (void*)&W, (void*)&vtag, (void*)&U, (void*)&T};
  hipLaunchCooperativeKernel((const void*)esn_scan, dim3(NBLK), dim3(256), args,
                             0, stream);
}